// Round 15
// baseline (1576.849 us; speedup 1.0000x reference)
//
#include <hip/hip_runtime.h>
#include <hip/hip_fp8.h>

typedef int v8i __attribute__((ext_vector_type(8)));
typedef float f32x4 __attribute__((ext_vector_type(4)));

#define N_TOTAL 262144
#define D 128
#define K_TOTAL 1024
#define BN 128
#define NBLK (N_TOTAL / BN)  // 2048
#define TILEB 8192  // 64 centroids x 128 dims x 1 B fp8, 16x16x128-operand order
#define NT 16

__device__ __forceinline__ unsigned f2fp8(float x) {
  return (unsigned)__hip_fp8_e4m3(x).__x;
}

// Kernel 1: codebook fp32 -> fp8 e4m3 packed in EXACT 16x16x128 B-operand
// order (lane l = kq*16 + c reads its 32 contiguous bytes at cgc*2048 + l*32).
// Also emits nm2[k] = -0.5*||m||^2 (exact fp32).
__global__ void prep_means(const float* __restrict__ means,
                           unsigned char* __restrict__ mbf8,
                           float* __restrict__ nm2) {
  int k = blockIdx.x, t = threadIdx.x;  // 1024 blocks x 64 threads
  int ts = k >> 6, c64 = k & 63;
  int cgc = c64 >> 4, c = c64 & 15;
  unsigned char* tb = mbf8 + ts * TILEB + cgc * 2048;
  float v0 = means[k * D + 2 * t];
  float v1 = means[k * D + 2 * t + 1];
#pragma unroll
  for (int i = 0; i < 2; ++i) {
    int d = 2 * t + i;
    int kq = d >> 5, rem = d & 31;
    tb[(kq * 16 + c) * 32 + rem] = (unsigned char)f2fp8(i ? v1 : v0);
  }
  float s = v0 * v0 + v1 * v1;
#pragma unroll
  for (int m = 32; m; m >>= 1) s += __shfl_down(s, m, 64);
  if (t == 0) nm2[k] = -0.5f * s;
}

union BOp {
  uint4 q[2];
  v8i v;
};

// Kernel 2: barrier-free main loop. B operands read DIRECTLY from L1/L2
// (codebook 128 KB, all waves stream tiles in the same order -> L1 temporal
// hits); no Bs LDS buffer, no staging, no in-loop barriers. LDS ~4.6 KB +
// VGPR<=64 -> 8 blocks/CU (grid = 2048 = 8x256). loss = x2 - 2*max(score).
__global__ __launch_bounds__(256, 8) void kmeans_main(
    const float* __restrict__ X, const unsigned char* __restrict__ mbf8,
    const float* __restrict__ nm2, float* __restrict__ partials) {
  __shared__ float m2s[K_TOTAL];  // 4 KB
  __shared__ float x2s[BN];       // 512 B
  __shared__ float wsum[4];

  const int t = threadIdx.x;
  const int l = t & 63;
  const int w = t >> 6;
  const int lr = l & 15;  // row-in-group for A; centroid-in-group for B
  const int kq = l >> 4;  // k-quarter (32-float slice of D=128)
  const long nbase = (long)blockIdx.x * BN;

  // ---- A fragments + exact fp32 ||x||^2 partials ----
  v8i af[2];
  float psq[2];
#pragma unroll
  for (int g = 0; g < 2; ++g) {
    const float* xr = X + (nbase + w * 32 + g * 16 + lr) * D + kq * 32;
    v8i av;
    float sq = 0.f;
#pragma unroll
    for (int j = 0; j < 8; ++j) {
      float4 v = *(const float4*)(xr + j * 4);
      sq = fmaf(v.x, v.x, sq);
      sq = fmaf(v.y, v.y, sq);
      sq = fmaf(v.z, v.z, sq);
      sq = fmaf(v.w, v.w, sq);
      av[j] = (int)(f2fp8(v.x) | (f2fp8(v.y) << 8) | (f2fp8(v.z) << 16) |
                    (f2fp8(v.w) << 24));
    }
    af[g] = av;
    psq[g] = sq;
  }
#pragma unroll
  for (int g = 0; g < 2; ++g) {
    float s2 = psq[g];
    s2 += __shfl_xor(s2, 16, 64);
    s2 += __shfl_xor(s2, 32, 64);
    if (kq == 0) x2s[w * 32 + g * 16 + lr] = s2;
  }

  // ---- stage nm2 into LDS (once) ----
  {
    float4 v = ((const float4*)nm2)[t];  // 256*4 = 1024
    *(float4*)(m2s + t * 4) = v;
  }

  float bs[8];  // running row maxes: [g*4 + reg]
#pragma unroll
  for (int e = 0; e < 8; ++e) bs[e] = -3.402823466e38f;

  __syncthreads();  // the ONLY pre-epilogue barrier: m2s + x2s visible

  // ---- barrier-free main loop: B direct from L1/L2 ----
  const char* bbase = (const char*)mbf8 + l * 32;
#pragma unroll
  for (int ts = 0; ts < NT; ++ts) {
#pragma unroll
    for (int cgc = 0; cgc < 4; ++cgc) {
      const char* p = bbase + ts * TILEB + cgc * 2048;
      BOp bu;
      bu.q[0] = *(const uint4*)(p);
      bu.q[1] = *(const uint4*)(p + 16);
      float m2v = m2s[ts * 64 + cgc * 16 + lr];
      f32x4 ci = {m2v, m2v, m2v, m2v};
#pragma unroll
      for (int g = 0; g < 2; ++g) {
        f32x4 acc = __builtin_amdgcn_mfma_scale_f32_16x16x128_f8f6f4(
            af[g], bu.v, ci, 0, 0, 0, 127, 0, 127);
#pragma unroll
        for (int e = 0; e < 4; ++e) bs[g * 4 + e] = fmaxf(bs[g * 4 + e], acc[e]);
      }
    }
  }

  // ---- per-row max across the 16 centroid-lanes, then loss contribution ----
  // slot (g, e) on lane (kq, lr) holds row g*16 + kq*4 + e (lanes lr share it)
  float lsum = 0.f;
#pragma unroll
  for (int e = 0; e < 8; ++e) {
    float m = bs[e];
#pragma unroll
    for (int s = 1; s < 16; s <<= 1) {
      float o = __shfl_xor(m, s, 64);
      m = fmaxf(m, o);
    }
    if (lr == 0) {
      int rowc = (e >> 2) * 16 + kq * 4 + (e & 3);
      lsum += x2s[w * 32 + rowc] - 2.0f * m;
    }
  }
#pragma unroll
  for (int s = 32; s; s >>= 1) lsum += __shfl_down(lsum, s, 64);
  if (l == 0) wsum[w] = lsum;
  __syncthreads();
  if (t == 0) partials[blockIdx.x] = wsum[0] + wsum[1] + wsum[2] + wsum[3];
}

// Kernel 3: deterministic fixed-order final reduction (double accum).
__global__ void reduce_loss(const float* __restrict__ partials,
                            float* __restrict__ out) {
  __shared__ double ws[4];
  int t = threadIdx.x;
  double s = 0.0;
  for (int i = t; i < NBLK; i += 256) s += (double)partials[i];
#pragma unroll
  for (int m = 32; m; m >>= 1) s += __shfl_down(s, m, 64);
  if ((t & 63) == 0) ws[t >> 6] = s;
  __syncthreads();
  if (t == 0) out[0] = (float)(ws[0] + ws[1] + ws[2] + ws[3]);
}

extern "C" void kernel_launch(void* const* d_in, const int* in_sizes, int n_in,
                              void* d_out, int out_size, void* d_ws,
                              size_t ws_size, hipStream_t stream) {
  const float* X = (const float*)d_in[0];
  const float* means = (const float*)d_in[1];
  float* out = (float*)d_out;
  char* ws = (char*)d_ws;
  unsigned char* mbf8 = (unsigned char*)ws;         // 131072 B
  float* nm2 = (float*)(ws + 131072);               // 4096 B
  float* partials = (float*)(ws + 131072 + 4096);   // 8192 B

  prep_means<<<K_TOTAL, 64, 0, stream>>>(means, mbf8, nm2);
  kmeans_main<<<NBLK, 256, 0, stream>>>(X, mbf8, nm2, partials);
  reduce_loss<<<1, 256, 0, stream>>>(partials, out);
}

// Round 16
// 65.704 us; speedup vs baseline: 23.9993x; 23.9993x over previous
//
#include <hip/hip_runtime.h>
#include <hip/hip_fp8.h>

typedef int v8i __attribute__((ext_vector_type(8)));
typedef float f32x4 __attribute__((ext_vector_type(4)));

#define N_TOTAL 262144
#define D 128
#define K_TOTAL 1024
#define BN 128
#define NBLK (N_TOTAL / BN)  // 2048
#define TILEB 8192  // 64 centroids x 128 dims x 1 B fp8, 16x16x128-operand order
#define NT 16

__device__ __forceinline__ unsigned f2fp8(float x) {
  return (unsigned)__hip_fp8_e4m3(x).__x;
}

// Kernel 1: codebook fp32 -> fp8 e4m3 packed in EXACT 16x16x128 B-operand
// order (lane l = kq*16 + c reads its 32 contiguous bytes at cgc*2048 + l*32).
// Also emits nm2[k] = -0.5*||m||^2 (exact fp32).
__global__ void prep_means(const float* __restrict__ means,
                           unsigned char* __restrict__ mbf8,
                           float* __restrict__ nm2) {
  int k = blockIdx.x, t = threadIdx.x;  // 1024 blocks x 64 threads
  int ts = k >> 6, c64 = k & 63;
  int cgc = c64 >> 4, c = c64 & 15;
  unsigned char* tb = mbf8 + ts * TILEB + cgc * 2048;
  float v0 = means[k * D + 2 * t];
  float v1 = means[k * D + 2 * t + 1];
#pragma unroll
  for (int i = 0; i < 2; ++i) {
    int d = 2 * t + i;
    int kq = d >> 5, rem = d & 31;
    tb[(kq * 16 + c) * 32 + rem] = (unsigned char)f2fp8(i ? v1 : v0);
  }
  float s = v0 * v0 + v1 * v1;
#pragma unroll
  for (int m = 32; m; m >>= 1) s += __shfl_down(s, m, 64);
  if (t == 0) nm2[k] = -0.5f * s;
}

union BOp {
  uint4 q[2];
  v8i v;
};

// Kernel 2: barrier-free main loop, B operands read DIRECTLY from L1/L2
// (codebook 128 KB, all waves stream in the same order). NO waves-per-EU
// launch_bounds arg (r15 lesson: it is an allocator cap -> spill). ts loop
// kept DYNAMIC so live range stays small; only cgc (4) unrolled.
// loss = x2 - 2*max_k(x.m - 0.5||m||^2), exact-fp32 x2/m2, fp8 dots.
__global__ __launch_bounds__(256) void kmeans_main(
    const float* __restrict__ X, const unsigned char* __restrict__ mbf8,
    const float* __restrict__ nm2, float* __restrict__ partials) {
  __shared__ float m2s[K_TOTAL];  // 4 KB
  __shared__ float x2s[BN];       // 512 B
  __shared__ float wsum[4];

  const int t = threadIdx.x;
  const int l = t & 63;
  const int w = t >> 6;
  const int lr = l & 15;  // row-in-group for A; centroid-in-group for B
  const int kq = l >> 4;  // k-quarter (32-float slice of D=128)
  const long nbase = (long)blockIdx.x * BN;

  // ---- A fragments + exact fp32 ||x||^2 partials ----
  v8i af[2];
  float psq[2];
#pragma unroll
  for (int g = 0; g < 2; ++g) {
    const float* xr = X + (nbase + w * 32 + g * 16 + lr) * D + kq * 32;
    v8i av;
    float sq = 0.f;
#pragma unroll
    for (int j = 0; j < 8; ++j) {
      float4 v = *(const float4*)(xr + j * 4);
      sq = fmaf(v.x, v.x, sq);
      sq = fmaf(v.y, v.y, sq);
      sq = fmaf(v.z, v.z, sq);
      sq = fmaf(v.w, v.w, sq);
      av[j] = (int)(f2fp8(v.x) | (f2fp8(v.y) << 8) | (f2fp8(v.z) << 16) |
                    (f2fp8(v.w) << 24));
    }
    af[g] = av;
    psq[g] = sq;
  }
#pragma unroll
  for (int g = 0; g < 2; ++g) {
    float s2 = psq[g];
    s2 += __shfl_xor(s2, 16, 64);
    s2 += __shfl_xor(s2, 32, 64);
    if (kq == 0) x2s[w * 32 + g * 16 + lr] = s2;
  }

  // ---- stage nm2 into LDS (once) ----
  {
    float4 v = ((const float4*)nm2)[t];  // 256*4 = 1024
    *(float4*)(m2s + t * 4) = v;
  }

  float bs[8];  // running row maxes: [g*4 + reg]
#pragma unroll
  for (int e = 0; e < 8; ++e) bs[e] = -3.402823466e38f;

  __syncthreads();  // the ONLY pre-epilogue barrier: m2s + x2s visible

  // ---- barrier-free main loop: B direct from L1/L2, ts dynamic ----
  const char* bbase = (const char*)mbf8 + l * 32;
  for (int ts = 0; ts < NT; ++ts) {
    const char* tp = bbase + ts * TILEB;
    const float* mp = m2s + ts * 64 + lr;
#pragma unroll
    for (int cgc = 0; cgc < 4; ++cgc) {
      const char* p = tp + cgc * 2048;
      BOp bu;
      bu.q[0] = *(const uint4*)(p);
      bu.q[1] = *(const uint4*)(p + 16);
      float m2v = mp[cgc * 16];
      f32x4 ci = {m2v, m2v, m2v, m2v};
#pragma unroll
      for (int g = 0; g < 2; ++g) {
        f32x4 acc = __builtin_amdgcn_mfma_scale_f32_16x16x128_f8f6f4(
            af[g], bu.v, ci, 0, 0, 0, 127, 0, 127);
#pragma unroll
        for (int e = 0; e < 4; ++e) bs[g * 4 + e] = fmaxf(bs[g * 4 + e], acc[e]);
      }
    }
  }

  // ---- per-row max across the 16 centroid-lanes, then loss contribution ----
  // slot (g, e) on lane (kq, lr) holds row g*16 + kq*4 + e (lanes lr share it)
  float lsum = 0.f;
#pragma unroll
  for (int e = 0; e < 8; ++e) {
    float m = bs[e];
#pragma unroll
    for (int s = 1; s < 16; s <<= 1) {
      float o = __shfl_xor(m, s, 64);
      m = fmaxf(m, o);
    }
    if (lr == 0) {
      int rowc = (e >> 2) * 16 + kq * 4 + (e & 3);
      lsum += x2s[w * 32 + rowc] - 2.0f * m;
    }
  }
#pragma unroll
  for (int s = 32; s; s >>= 1) lsum += __shfl_down(lsum, s, 64);
  if (l == 0) wsum[w] = lsum;
  __syncthreads();
  if (t == 0) partials[blockIdx.x] = wsum[0] + wsum[1] + wsum[2] + wsum[3];
}

// Kernel 3: deterministic fixed-order final reduction (double accum).
__global__ void reduce_loss(const float* __restrict__ partials,
                            float* __restrict__ out) {
  __shared__ double ws[4];
  int t = threadIdx.x;
  double s = 0.0;
  for (int i = t; i < NBLK; i += 256) s += (double)partials[i];
#pragma unroll
  for (int m = 32; m; m >>= 1) s += __shfl_down(s, m, 64);
  if ((t & 63) == 0) ws[t >> 6] = s;
  __syncthreads();
  if (t == 0) out[0] = (float)(ws[0] + ws[1] + ws[2] + ws[3]);
}

extern "C" void kernel_launch(void* const* d_in, const int* in_sizes, int n_in,
                              void* d_out, int out_size, void* d_ws,
                              size_t ws_size, hipStream_t stream) {
  const float* X = (const float*)d_in[0];
  const float* means = (const float*)d_in[1];
  float* out = (float*)d_out;
  char* ws = (char*)d_ws;
  unsigned char* mbf8 = (unsigned char*)ws;         // 131072 B
  float* nm2 = (float*)(ws + 131072);               // 4096 B
  float* partials = (float*)(ws + 131072 + 4096);   // 8192 B

  prep_means<<<K_TOTAL, 64, 0, stream>>>(means, mbf8, nm2);
  kmeans_main<<<NBLK, 256, 0, stream>>>(X, mbf8, nm2, partials);
  reduce_loss<<<1, 256, 0, stream>>>(partials, out);
}